// Round 9
// baseline (402.131 us; speedup 1.0000x reference)
//
#include <hip/hip_runtime.h>
#include <hip/hip_bf16.h>

#define ALPHA_ 0.2f
#define EPS_ 1e-12f

typedef short short8 __attribute__((ext_vector_type(8)));
typedef unsigned short ushort4v __attribute__((ext_vector_type(4)));
typedef float f32x4 __attribute__((ext_vector_type(4)));

constexpr int BB = 16, KK = 16, DD = 256, NNEG = 16384;
constexpr int ITERS = 4;   // Newton-Schulz iterations (even; start at XB => final lands in XB)

// ---- workspace layout (float offsets) ---- total 5,309,440 floats (proven size)
constexpr size_t OFF_NL    = 0;         // 2M floats: neg-lo (overlays XA after Newton)
constexpr size_t OFF_XA_H  = 1048576;   // pong
constexpr size_t OFF_XA_L  = 1572864;
constexpr size_t OFF_XB_H  = 2097152;   // ping; FINAL A hi (never overlaid)
constexpr size_t OFF_XB_L  = 2621440;   // FINAL A lo
constexpr size_t OFF_NH    = 3145728;   // 2M floats: neg-hi (overlays T+S after Newton)
constexpr size_t OFF_T_H   = 3145728;
constexpr size_t OFF_C01   = 3149824;   // c0[16], c1[16] (inside T region; dead before Newton writes T)
constexpr size_t OFF_T_L   = 3670016;
constexpr size_t OFF_S_H   = 4194304;
constexpr size_t OFF_S_L   = 4718592;
constexpr size_t OFF_PA_H  = 5242880;   // 65536 ushorts
constexpr size_t OFF_PA_L  = 5275648;
constexpr size_t OFF_PAP   = 5308416;
constexpr size_t OFF_DPOS2 = 5308672;
constexpr size_t OFF_MINA  = 5308928;
constexpr size_t OFF_MINV  = 5309184;

// ---------- bf16 split helpers (RNE) ----------
__device__ inline unsigned short bf_hi(float x) {
    unsigned u = __float_as_uint(x);
    return (unsigned short)((u + 0x7fffu + ((u >> 16) & 1u)) >> 16);
}
__device__ inline float bf_tof(unsigned short h) { return __uint_as_float(((unsigned)h) << 16); }
__device__ inline void split2(float x, unsigned short& h, unsigned short& l) {
    h = bf_hi(x); l = bf_hi(x - bf_tof(h));
}

// ---------- bound: Gershgorin + 12-step power iteration -> degree-2 init coefficients ----------
__global__ __launch_bounds__(256) void kbound(const float* __restrict__ Sig, float* __restrict__ c01) {
    int b = blockIdx.x, t = threadIdx.x;
    const float* S = Sig + (size_t)b * 65536;
    __shared__ float v[256];
    __shared__ float red[256];
    float cs = 0.f;
    for (int i = 0; i < 256; ++i) cs += fabsf(S[(size_t)i * 256 + t]);
    red[t] = cs; __syncthreads();
    for (int s = 128; s > 0; s >>= 1) { if (t < s) red[t] = fmaxf(red[t], red[t + s]); __syncthreads(); }
    float G = red[0]; __syncthreads();
    v[t] = 1.f; __syncthreads();
    for (int it = 0; it < 12; ++it) {
        float wv = 0.f;
        for (int i = 0; i < 256; ++i) wv = fmaf(S[(size_t)i * 256 + t], v[i], wv);
        red[t] = wv * wv; __syncthreads();
        for (int s = 128; s > 0; s >>= 1) { if (t < s) red[t] += red[t + s]; __syncthreads(); }
        float nrm = sqrtf(red[0]); __syncthreads();
        v[t] = wv / nrm; __syncthreads();
    }
    float w2 = 0.f;
    for (int i = 0; i < 256; ++i) w2 = fmaf(S[(size_t)i * 256 + t], v[i], w2);
    red[t] = w2 * v[t]; __syncthreads();
    for (int s = 128; s > 0; s >>= 1) { if (t < s) red[t] += red[t + s]; __syncthreads(); }
    if (t == 0) {
        float lam = red[0];                         // Rayleigh quotient (<= lambda_max)
        float Bb = fminf(G, 1.06f * lam + 0.05f);   // safe upper estimate
        float c1 = -2.f / (Bb + (Bb + 1.f) * (Bb + 1.f) * 0.25f);
        c01[b] = -c1 * (Bb + 1.f); c01[16 + b] = c1;
    }
}

// ---------- prep: split S; X0 = c0*I + c1*S -> XB (split) ----------
__global__ __launch_bounds__(256) void kinit(const float* __restrict__ Sig, float* __restrict__ ws,
                                             const float* __restrict__ c01) {
    int idx = blockIdx.x * 256 + threadIdx.x;
    int b = idx >> 16, rc = idx & 65535;
    int r = rc >> 8, c = rc & 255;
    float v = Sig[idx];
    unsigned short h, l;
    split2(v, h, l);
    ((unsigned short*)(ws + OFF_S_H))[idx] = h; ((unsigned short*)(ws + OFF_S_L))[idx] = l;
    float x0 = c01[16 + b] * v + ((r == c) ? c01[b] : 0.f);
    split2(x0, h, l);
    ((unsigned short*)(ws + OFF_XB_H))[idx] = h; ((unsigned short*)(ws + OFF_XB_L))[idx] = l;
}

// ---------- batched 256x256 MFMA split GEMM, 32x64 tiles, XCD-local b mapping ----------
__global__ __launch_bounds__(256) void gemm_mfma(const unsigned short* __restrict__ Ah,
                                                 const unsigned short* __restrict__ Al,
                                                 const unsigned short* __restrict__ Bh,
                                                 const unsigned short* __restrict__ Bl,
                                                 unsigned short* __restrict__ Ch,
                                                 unsigned short* __restrict__ Cl, int mode2i) {
    int lin = blockIdx.x;
    int x = lin & 7, q = lin >> 3;                  // XCD x owns b in {2x, 2x+1}
    int b = x * 2 + (q >> 5);
    int tile = q & 31;
    int i0 = (tile >> 2) * 32, j0 = (tile & 3) * 64;
    size_t base = (size_t)b * 65536;
    int t = threadIdx.x, lane = t & 63, w = t >> 6;
    int l15 = lane & 15, lg = lane >> 4;
    f32x4 acc[2] = {};
    int ar0 = i0 + l15;
    int br  = j0 + w * 16 + l15;
    #pragma unroll
    for (int e0 = 0; e0 < 256; e0 += 32) {
        int eo = e0 + 8 * lg;
        short8 a_h[2], a_l[2];
        #pragma unroll
        for (int m = 0; m < 2; ++m) {
            size_t off = base + (size_t)(ar0 + m * 16) * 256 + eo;
            a_h[m] = *reinterpret_cast<const short8*>(Ah + off);
            a_l[m] = *reinterpret_cast<const short8*>(Al + off);
        }
        size_t boff = base + (size_t)br * 256 + eo;     // symmetric: row == col
        short8 b_h = *reinterpret_cast<const short8*>(Bh + boff);
        short8 b_l = *reinterpret_cast<const short8*>(Bl + boff);
        #pragma unroll
        for (int m = 0; m < 2; ++m) {
            acc[m] = __builtin_amdgcn_mfma_f32_16x16x32_bf16(a_h[m], b_h, acc[m], 0, 0, 0);
            acc[m] = __builtin_amdgcn_mfma_f32_16x16x32_bf16(a_h[m], b_l, acc[m], 0, 0, 0);
            acc[m] = __builtin_amdgcn_mfma_f32_16x16x32_bf16(a_l[m], b_h, acc[m], 0, 0, 0);
        }
    }
    #pragma unroll
    for (int m = 0; m < 2; ++m)
        #pragma unroll
        for (int r = 0; r < 4; ++r) {
            int row = i0 + m * 16 + 4 * lg + r;
            int col = j0 + w * 16 + l15;
            float v = acc[m][r];
            if (mode2i) v = ((row == col) ? 2.f : 0.f) - v;
            unsigned short h, l; split2(v, h, l);
            size_t off = base + (size_t)row * 256 + col;
            Ch[off] = h; Cl[off] = l;
        }
}

// ---------- negatives pre-split (once) + min-buffer init ----------
__global__ __launch_bounds__(256) void knegsplit(const float* __restrict__ negs,
                                                 unsigned short* __restrict__ NH,
                                                 unsigned short* __restrict__ NL,
                                                 unsigned* __restrict__ mina,
                                                 unsigned* __restrict__ minv) {
    size_t i8 = ((size_t)blockIdx.x * 256 + threadIdx.x) * 8;
    f32x4 v0 = *reinterpret_cast<const f32x4*>(negs + i8);
    f32x4 v1 = *reinterpret_cast<const f32x4*>(negs + i8 + 4);
    short8 h, l;
    #pragma unroll
    for (int j = 0; j < 4; ++j) {
        unsigned short hh, ll;
        split2(v0[j], hh, ll); h[j] = (short)hh; l[j] = (short)ll;
        split2(v1[j], hh, ll); h[4 + j] = (short)hh; l[4 + j] = (short)ll;
    }
    *reinterpret_cast<short8*>(NH + i8) = h;
    *reinterpret_cast<short8*>(NL + i8) = l;
    if (blockIdx.x == 0) {
        mina[threadIdx.x] = 0x7f800000u; minv[threadIdx.x] = 0x7f800000u;
    }
}

// ---------- per (b,k): PA row (split), pAp, dpos2 ----------
__global__ __launch_bounds__(256) void k2(const float* __restrict__ Z1, const float* __restrict__ Z2,
                                          const int* __restrict__ match,
                                          const unsigned short* __restrict__ AH,
                                          const unsigned short* __restrict__ AL,
                                          float* __restrict__ ws) {
    int bk = blockIdx.x; int b = bk >> 4; int t = threadIdx.x;
    const unsigned short* Ah = AH + (size_t)b * 65536;
    const unsigned short* Al = AL + (size_t)b * 65536;
    __shared__ float z[DD], df[DD];
    __shared__ float red[256];
    int m = match[bk];
    float zv = Z1[(size_t)bk * DD + t];
    float qv = Z2[((size_t)b * KK + m) * DD + t];
    z[t] = zv; df[t] = zv - qv;
    __syncthreads();
    float pa = 0.f, da = 0.f;
    for (int e = 0; e < DD; ++e) {
        float Ae = bf_tof(Ah[(size_t)e * 256 + t]) + bf_tof(Al[(size_t)e * 256 + t]);
        pa = fmaf(z[e], Ae, pa);
        da = fmaf(df[e], Ae, da);
    }
    unsigned short ph, pl; split2(pa, ph, pl);
    ((unsigned short*)(ws + OFF_PA_H))[(size_t)bk * 256 + t] = ph;
    ((unsigned short*)(ws + OFF_PA_L))[(size_t)bk * 256 + t] = pl;
    float dfv = df[t];
    red[t] = pa * zv; __syncthreads();
    for (int s = 128; s > 0; s >>= 1) { if (t < s) red[t] += red[t + s]; __syncthreads(); }
    float pAp = red[0]; __syncthreads();
    red[t] = da * dfv; __syncthreads();
    for (int s = 128; s > 0; s >>= 1) { if (t < s) red[t] += red[t + s]; __syncthreads(); }
    if (t == 0) {
        ws[OFF_PAP + bk]   = pAp;
        ws[OFF_DPOS2 + bk] = fmaxf(red[0], EPS_);
    }
}

// ---------- main kernel: 4-wave blocks (1 wave/SIMD), n-tile 64, decoupled barriers ----------
// Wave w owns f-tiles {4w..4w+3}; all 4 n-subtiles j. PA tile on wave 0 only.
// acc[4][4]=64 AGPR + accp[4]=16; no launch_bounds cap (spill-proof).
__global__ __launch_bounds__(256) void k3(const unsigned short* __restrict__ Ahi,
                                          const unsigned short* __restrict__ Alo,
                                          const unsigned short* __restrict__ PAh,
                                          const unsigned short* __restrict__ PAl,
                                          const unsigned short* __restrict__ NH,
                                          const unsigned short* __restrict__ NL,
                                          const float* __restrict__ pap,
                                          const float* __restrict__ dpos2,
                                          unsigned* __restrict__ mina,
                                          unsigned* __restrict__ minv) {
    __shared__ float smem[5120];                       // 20 KB: 4 ushort buffers [64][40]
    unsigned short* BH0 = (unsigned short*)smem;
    unsigned short* BL0 = BH0 + 2560;
    unsigned short* BH1 = BL0 + 2560;
    unsigned short* BL1 = BH1 + 2560;

    int lin = blockIdx.x;
    int x  = lin & 7;
    int q  = lin >> 3;
    int b  = q >> 5;
    int n0 = (x * 32 + (q & 31)) * 64;                 // XCD-local 2048-n slice
    int t = threadIdx.x, lane = t & 63, w = t >> 6;
    int l15 = lane & 15, lg = lane >> 4;
    const unsigned short* Ab  = Ahi + (size_t)b * 65536;
    const unsigned short* Al_ = Alo + (size_t)b * 65536;
    const unsigned short* Nh  = NH + (size_t)n0 * 256;
    const unsigned short* Nl  = NL + (size_t)n0 * 256;

    int srow = t >> 2, sq = t & 3;                     // staging: neg row, 16B quarter
    const unsigned short* NhS = Nh + (size_t)srow * 256 + sq * 8;
    const unsigned short* NlS = Nl + (size_t)srow * 256 + sq * 8;
    int soff = srow * 40 + sq * 8;

    const unsigned short* aBh = Ab  + (size_t)(w * 64 + l15) * 256 + 8 * lg;   // f-tile base (i adds i*16*256)
    const unsigned short* aBl = Al_ + (size_t)(w * 64 + l15) * 256 + 8 * lg;
    const unsigned short* pph = PAh + (size_t)b * 4096 + (size_t)l15 * 256 + 8 * lg;
    const unsigned short* ppl = PAl + (size_t)b * 4096 + (size_t)l15 * 256 + 8 * lg;

    f32x4 acc[4][4] = {};
    f32x4 accp[4] = {};

    // prologue: stage chunk 0 into buf0
    short8 sH = *reinterpret_cast<const short8*>(NhS);
    short8 sL = *reinterpret_cast<const short8*>(NlS);
    *reinterpret_cast<short8*>(BH0 + soff) = sH;
    *reinterpret_cast<short8*>(BL0 + soff) = sL;
    __syncthreads();

    #pragma unroll
    for (int c = 0; c < 8; ++c) {
        unsigned short* cH = (c & 1) ? BH1 : BH0;
        unsigned short* cL = (c & 1) ? BL1 : BL0;
        unsigned short* nH = (c & 1) ? BH0 : BH1;
        unsigned short* nL = (c & 1) ? BL0 : BL1;
        if (c < 7) {                                    // early-issue next-chunk staging loads
            sH = *reinterpret_cast<const short8*>(NhS + (c + 1) * 32);
            sL = *reinterpret_cast<const short8*>(NlS + (c + 1) * 32);
        }
        short8 ah[4], al[4];
        #pragma unroll
        for (int i = 0; i < 4; ++i) {                   // a-frags: 4 f-tiles, L2-hot
            ah[i] = *reinterpret_cast<const short8*>(aBh + i * 16 * 256 + c * 32);
            al[i] = *reinterpret_cast<const short8*>(aBl + i * 16 * 256 + c * 32);
        }
        short8 ph_ = {}, pl_ = {};
        if (w == 0) {
            ph_ = *reinterpret_cast<const short8*>(pph + c * 32);
            pl_ = *reinterpret_cast<const short8*>(ppl + c * 32);
        }
        #pragma unroll
        for (int j = 0; j < 4; ++j) {                   // j-outer: LDS read once per j
            short8 bh = *reinterpret_cast<const short8*>(cH + (j * 16 + l15) * 40 + 8 * lg);
            short8 bl = *reinterpret_cast<const short8*>(cL + (j * 16 + l15) * 40 + 8 * lg);
            #pragma unroll
            for (int i = 0; i < 4; ++i) {
                acc[i][j] = __builtin_amdgcn_mfma_f32_16x16x32_bf16(ah[i], bh, acc[i][j], 0, 0, 0);
                acc[i][j] = __builtin_amdgcn_mfma_f32_16x16x32_bf16(ah[i], bl, acc[i][j], 0, 0, 0);
                acc[i][j] = __builtin_amdgcn_mfma_f32_16x16x32_bf16(al[i], bh, acc[i][j], 0, 0, 0);
            }
            if (w == 0) {
                accp[j] = __builtin_amdgcn_mfma_f32_16x16x32_bf16(ph_, bh, accp[j], 0, 0, 0);
                accp[j] = __builtin_amdgcn_mfma_f32_16x16x32_bf16(ph_, bl, accp[j], 0, 0, 0);
                accp[j] = __builtin_amdgcn_mfma_f32_16x16x32_bf16(pl_, bh, accp[j], 0, 0, 0);
            }
        }
        if (c < 7) {                                    // write next buffer (distinct from cur)
            *reinterpret_cast<short8*>(nH + soff) = sH;
            *reinterpret_cast<short8*>(nL + soff) = sL;
        }
        __syncthreads();                                // couples only 4 waves (1/SIMD)
    }

    // ---- epilogue (smem reused after final barrier) ----
    float* pAn_l = smem;            // [64][17] = 1088
    float* nAnp  = smem + 1088;     // [4][64]
    float* nAn_l = smem + 1344;     // [64]
    float* reda  = smem + 1408;     // [256]
    float* redv  = smem + 1664;     // [256]

    if (w == 0) {
        #pragma unroll
        for (int j = 0; j < 4; ++j) {
            int n = j * 16 + l15;
            #pragma unroll
            for (int r = 0; r < 4; ++r)
                pAn_l[n * 17 + 4 * lg + r] = accp[j][r];    // pAn[n][k], k=4lg+r
        }
    }
    #pragma unroll
    for (int j = 0; j < 4; ++j) {
        int n = j * 16 + l15;
        float p = 0.f;
        #pragma unroll
        for (int i = 0; i < 4; ++i) {
            int fb = (w * 4 + i) * 16 + 4 * lg;
            ushort4v wh = *reinterpret_cast<const ushort4v*>(NH + (size_t)(n0 + n) * 256 + fb);
            ushort4v wl = *reinterpret_cast<const ushort4v*>(NL + (size_t)(n0 + n) * 256 + fb);
            #pragma unroll
            for (int r = 0; r < 4; ++r)
                p = fmaf(acc[i][j][r], bf_tof(wh[r]) + bf_tof(wl[r]), p);
        }
        p += __shfl_xor(p, 16);                         // reduce over lg
        p += __shfl_xor(p, 32);
        if (lane < 16) nAnp[w * 64 + n] = p;
    }
    __syncthreads();
    if (t < 64) nAn_l[t] = nAnp[t] + nAnp[64 + t] + nAnp[128 + t] + nAnp[192 + t];
    __syncthreads();
    int tx = t & 15, ty = t >> 4;                       // ty 0..15, 4 n each
    float pApk = pap[b * 16 + tx];
    float dp2  = dpos2[b * 16 + tx];
    float mn_a = __uint_as_float(0x7f800000u), mn_v = mn_a;
    #pragma unroll
    for (int ii = 0; ii < 4; ++ii) {
        int n = ty * 4 + ii;
        float d2v = pApk - 2.f * pAn_l[n * 17 + tx] + nAn_l[n];
        float cc = fmaxf(d2v, EPS_);
        mn_a = fminf(mn_a, cc);
        if (cc > dp2) mn_v = fminf(mn_v, cc);
    }
    reda[ty * 16 + tx] = mn_a; redv[ty * 16 + tx] = mn_v;
    __syncthreads();
    if (ty == 0) {
        float ra = reda[tx], rv = redv[tx];
        #pragma unroll
        for (int y = 1; y < 16; ++y) {
            ra = fminf(ra, reda[y * 16 + tx]);
            rv = fminf(rv, redv[y * 16 + tx]);
        }
        atomicMin(&mina[b * 16 + tx], __float_as_uint(ra));
        atomicMin(&minv[b * 16 + tx], __float_as_uint(rv));
    }
}

// ---------- final loss ----------
__global__ __launch_bounds__(256) void k5(const float* __restrict__ dpos2,
                                          const unsigned* __restrict__ mina,
                                          const unsigned* __restrict__ minv,
                                          float* __restrict__ out) {
    int t = threadIdx.x;
    __shared__ float red[256];
    float dp = sqrtf(dpos2[t]);
    unsigned mv = minv[t], ma = mina[t];
    unsigned sel = (mv < 0x7f800000u) ? mv : ma;
    float dn = sqrtf(__uint_as_float(sel));
    red[t] = fmaxf(dp - dn + ALPHA_, 0.f);
    __syncthreads();
    for (int s = 128; s > 0; s >>= 1) { if (t < s) red[t] += red[t + s]; __syncthreads(); }
    if (t == 0) out[0] = red[0] * (1.f / 256.f);
}

extern "C" void kernel_launch(void* const* d_in, const int* in_sizes, int n_in,
                              void* d_out, int out_size, void* d_ws, size_t ws_size,
                              hipStream_t stream) {
    (void)in_sizes; (void)n_in; (void)out_size; (void)ws_size;
    const float* Z1   = (const float*)d_in[0];
    const float* Z2   = (const float*)d_in[1];
    const int*   mat  = (const int*)d_in[2];
    const float* negs = (const float*)d_in[3];
    const float* Sig  = (const float*)d_in[4];
    float* ws = (float*)d_ws;
    unsigned short* S_H  = (unsigned short*)(ws + OFF_S_H);
    unsigned short* S_L  = (unsigned short*)(ws + OFF_S_L);
    unsigned short* XA_H = (unsigned short*)(ws + OFF_XA_H);
    unsigned short* XA_L = (unsigned short*)(ws + OFF_XA_L);
    unsigned short* XB_H = (unsigned short*)(ws + OFF_XB_H);
    unsigned short* XB_L = (unsigned short*)(ws + OFF_XB_L);
    unsigned short* T_H  = (unsigned short*)(ws + OFF_T_H);
    unsigned short* T_L  = (unsigned short*)(ws + OFF_T_L);
    unsigned short* PA_H = (unsigned short*)(ws + OFF_PA_H);
    unsigned short* PA_L = (unsigned short*)(ws + OFF_PA_L);
    unsigned short* NH   = (unsigned short*)(ws + OFF_NH);
    unsigned short* NL   = (unsigned short*)(ws + OFF_NL);
    unsigned* mina = (unsigned*)(ws + OFF_MINA);
    unsigned* minv = (unsigned*)(ws + OFF_MINV);
    float* out = (float*)d_out;

    kbound<<<BB, 256, 0, stream>>>(Sig, ws + OFF_C01);
    kinit<<<4096, 256, 0, stream>>>(Sig, ws, ws + OFF_C01);

    unsigned short* pah = XB_H; unsigned short* pal = XB_L;   // start at XB: even ITERS => final in XB
    unsigned short* pbh = XA_H; unsigned short* pbl = XA_L;
    for (int it = 0; it < ITERS; ++it) {
        gemm_mfma<<<512, 256, 0, stream>>>(S_H, S_L, pah, pal, T_H, T_L, 1);   // T = 2I - S@X
        gemm_mfma<<<512, 256, 0, stream>>>(pah, pal, T_H, T_L, pbh, pbl, 0);   // X' = X@T
        unsigned short* th = pah; pah = pbh; pbh = th;
        unsigned short* tl = pal; pal = pbl; pbl = tl;
    }
    // ITERS=4 (even) => final split inverse in XB_H/XB_L (== pah/pal); XA/T/S now dead

    knegsplit<<<NNEG * DD / 8 / 256, 256, 0, stream>>>(negs, NH, NL, mina, minv);
    k2<<<BB * KK, 256, 0, stream>>>(Z1, Z2, mat, pah, pal, ws);
    k3<<<BB * NNEG / 64, 256, 0, stream>>>(pah, pal, PA_H, PA_L, NH, NL,
                                           ws + OFF_PAP, ws + OFF_DPOS2, mina, minv);
    k5<<<1, 256, 0, stream>>>(ws + OFF_DPOS2, mina, minv, out);
}